// Round 1
// baseline (70.055 us; speedup 1.0000x reference)
//
#include <hip/hip_runtime.h>
#include <hip/hip_bf16.h>
#include <math.h>

#define SQRT2F 1.41421356237309504880f

// One wave (64 lanes) does everything.
// h, g: 32 floats each. out: 1 float.
__global__ void __launch_bounds__(64)
wavelet_reg_kernel(const float* __restrict__ h,
                   const float* __restrict__ g,
                   float* __restrict__ out) {
    const int lane = threadIdx.x;  // 0..63

    __shared__ float hs[32];
    __shared__ float gs[32];

    float hv = 0.0f, gv = 0.0f;
    if (lane < 32) {
        hv = h[lane];
        gv = g[lane];
        hs[lane] = hv;
        gs[lane] = gv;
    }
    __syncthreads();

    // ---- wave reductions: sum(h), sum(g), dot(h,h) ----
    float sum_h = hv;
    float sum_g = gv;
    float dot_hh = hv * hv;
    #pragma unroll
    for (int off = 32; off >= 1; off >>= 1) {
        sum_h  += __shfl_xor(sum_h,  off);
        sum_g  += __shfl_xor(sum_g,  off);
        dot_hh += __shfl_xor(dot_hh, off);
    }

    // ---- l4: autocorrelation at even lags d = 2k, k = 1..15 ----
    // full[L-1 + d] = sum_i h[i] * h[i+d], valid i in [0, 31-d]
    float l4term = 0.0f;
    if (lane >= 1 && lane <= 15) {
        const int d = 2 * lane;
        float a = 0.0f;
        for (int i = 0; i + d < 32; ++i) {
            a = fmaf(hs[i], hs[i + d], a);
        }
        l4term = a * a;
    }

    // ---- l5: vanishing moments, p = lane+1 for lane in [0,16) ----
    // moment_p = sum_r r^(p-1) * g[r];  term = (moment_p * sqrt2 / 2^p)^2
    float l5term = 0.0f;
    if (lane < 16) {
        const int p = lane + 1;
        float m = 0.0f;
        for (int r = 0; r < 32; ++r) {
            // r^(p-1) via iterated multiply; p=1 -> 1.0 (incl. r=0: 0^0 = 1)
            float pw = 1.0f;
            const float rf = (float)r;
            for (int j = 0; j < p - 1; ++j) pw *= rf;
            m = fmaf(pw, gs[r], m);
        }
        const float norm = SQRT2F / exp2f((float)p);
        const float t = m * norm;
        l5term = t * t;
    }

    // ---- combine ----
    float partial = l4term + l5term;
    #pragma unroll
    for (int off = 32; off >= 1; off >>= 1) {
        partial += __shfl_xor(partial, off);
    }

    if (lane == 0) {
        const float d1 = sum_h - SQRT2F;
        const float l1 = d1 * d1;
        const float l2 = sum_g * sum_g;
        const float d3 = dot_hh - 1.0f;
        const float l3 = d3 * d3;
        out[0] = l1 + l2 + l3 + partial;
    }
}

extern "C" void kernel_launch(void* const* d_in, const int* in_sizes, int n_in,
                              void* d_out, int out_size, void* d_ws, size_t ws_size,
                              hipStream_t stream) {
    const float* h = (const float*)d_in[0];
    const float* g = (const float*)d_in[1];
    float* out = (float*)d_out;
    wavelet_reg_kernel<<<1, 64, 0, stream>>>(h, g, out);
}